// Round 2
// baseline (3324.029 us; speedup 1.0000x reference)
//
#include <hip/hip_runtime.h>
#include <stdint.h>
#include <stddef.h>

#define Bb   256
#define Tt   500
#define NIN  128
#define NH   512
#define NOUT 64

typedef __attribute__((ext_vector_type(8))) short  short8;   // 8 bf16 (4 VGPRs)
typedef __attribute__((ext_vector_type(4))) float  float4v;
typedef __attribute__((ext_vector_type(2))) float  float2v;

__device__ __forceinline__ unsigned short f2b(float f) {
    union { float f; unsigned u; } v; v.f = f;
    unsigned u = v.u;
    unsigned r = (u + 0x7FFFu + ((u >> 16) & 1u)) >> 16;  // RNE
    return (unsigned short)r;
}

// load 8 consecutive fp32 (16B-aligned) and convert to a bf16x8 fragment
__device__ __forceinline__ short8 cvt8(const float* __restrict__ p) {
    const float4v a = *(const float4v*)p;
    const float4v b = *(const float4v*)(p + 4);
    short8 r;
    r[0] = (short)f2b(a[0]); r[1] = (short)f2b(a[1]);
    r[2] = (short)f2b(a[2]); r[3] = (short)f2b(a[3]);
    r[4] = (short)f2b(b[0]); r[5] = (short)f2b(b[1]);
    r[6] = (short)f2b(b[2]); r[7] = (short)f2b(b[3]);
    return r;
}

// 16B bf16 fragment via two relaxed agent-scope u64 atomic loads
// (coherence-point routed -> always fresh, zero cache-maintenance ops).
__device__ __forceinline__ short8 ld_frag_cp(const unsigned short* p) {
    unsigned long long lo = __hip_atomic_load((const unsigned long long*)p,
                                              __ATOMIC_RELAXED, __HIP_MEMORY_SCOPE_AGENT);
    unsigned long long hi = __hip_atomic_load((const unsigned long long*)(p + 4),
                                              __ATOMIC_RELAXED, __HIP_MEMORY_SCOPE_AGENT);
    union { unsigned long long u[2]; short8 s; } v;
    v.u[0] = lo; v.u[1] = hi;
    return v.s;
}

__global__ void init_flags_kernel(unsigned int* flags) {
    flags[blockIdx.x * 256 + threadIdx.x] = 0u;  // 1024 = 16 groups x 64 wave-flags
}

// Persistent recurrent kernel with FUSED output projection. 256 wgs x 256 thr.
// wg -> (g = wg&15 batch group of 16 rows [XCD co-location swizzle],
//        s = wg>>4  32-col hidden slice).
// Sync protocol: per-WAVE flags (64 per group). Each wave: Hx atomic stores ->
// vmcnt(0) -> own flag (relaxed agent). Each consumer wave polls all 64 group
// flags itself (lane l -> flag l) -> no inter-wave barriers on the sync path;
// only the Cred-reduction __syncthreads remains per step.
// Safety: a wave's LDS (Cred/Cred2) reads precede its flag store in program
// order; any LDS write at t+1 is control-dependent on observing all 64
// flags >= t+1, which happen-after every wave's reads at t. Monotonic flags.
// Fused out-proj: slices s<4 also compute out_{t-1} = h_{t-1} @ Wout^T using
// the SAME ah fragments (K-split across waves), 2nd LDS reduce overlapped
// with the Hx store drain, fp32 stores after the flag release.
__global__ void __launch_bounds__(256) rnn_persist(
    const float* __restrict__ x,      // [B][T][NIN]
    const float* __restrict__ h0,     // [B][NH]
    const float* __restrict__ Wih,    // [NH][NIN]
    const float* __restrict__ Whh,    // [NH][NH]
    const float* __restrict__ bih,    // [NH]
    const float* __restrict__ bhh,    // [NH]
    const float* __restrict__ alpha,  // [NH]
    const float* __restrict__ Wout,   // [NOUT][NH]
    const float* __restrict__ bout,   // [NOUT]
    float* __restrict__ out,          // full output buffer
    unsigned short* __restrict__ Hx,  // ws: [2][B][NH] bf16
    unsigned int* __restrict__ flags) // ws: [16 groups][64 wave-flags]
{
    const int wg  = blockIdx.x;
    const int g   = wg & 15;   // batch group (same XCD under round-robin)
    const int s   = wg >> 4;   // hidden slice
    const int r0  = g << 4;    // first batch row
    const int c0  = s << 5;    // first hidden col
    const int tid = threadIdx.x;
    const int w   = tid >> 6;  // wave 0..3 (K-split)
    const int l   = tid & 63;
    const int l15 = l & 15;
    const int q   = l >> 4;
    const bool do_out = (s < 4);   // wg-uniform

    // partial-C exchange: [wave][ntile][quad][lane15][reg] fp32
    __shared__ float Cred[4 * 2 * 4 * 16 * 4];
    // out-proj partials: [wave][quad][lane15][reg] fp32
    __shared__ float Cred2[4 * 4 * 16 * 4];

    // ---- stationary weight fragments (loaded once, fp32 -> bf16) ----
    // B-frag layout: B[k][n], n = lane&15, k = quad*8 + j (8 contiguous k)
    short8 fw_hh[2][4], fw_ih[2], fw_out[4];
    for (int nt = 0; nt < 2; ++nt) {
        for (int i = 0; i < 4; ++i) {
            const float* p = Whh + (size_t)(c0 + nt * 16 + l15) * NH
                                 + (4 * w + i) * 32 + q * 8;
            fw_hh[nt][i] = cvt8(p);
        }
        fw_ih[nt] = cvt8(Wih + (size_t)(c0 + nt * 16 + l15) * NIN + w * 32 + q * 8);
    }
    if (do_out) {
        for (int i = 0; i < 4; ++i)
            fw_out[i] = cvt8(Wout + (size_t)(s * 16 + l15) * NH + (4 * w + i) * 32 + q * 8);
    }

    // ---- per-thread epilogue state (thread -> (row, 2 cols)) ----
    const int urow = tid >> 4;           // 0..15 batch-local row
    const int ucol = (tid & 15) * 2;     // 0..30 col pair within slice
    const int oc   = tid & 15;           // out col within 16-col tile
    const int gb   = r0 + urow;          // global batch row
    float hcur0 = h0[(size_t)gb * NH + c0 + ucol];
    float hcur1 = h0[(size_t)gb * NH + c0 + ucol + 1];
    const float bias0 = bih[c0 + ucol]     + bhh[c0 + ucol];
    const float bias1 = bih[c0 + ucol + 1] + bhh[c0 + ucol + 1];
    const float al0 = alpha[c0 + ucol], al1 = alpha[c0 + ucol + 1];
    const float ob  = do_out ? bout[s * 16 + oc] : 0.f;

    float* hid_out   = out;                                   // [B][T][NH]
    float* outp      = out + (size_t)Bb * Tt * NH;            // [B][T][NOUT]
    float* final_out = outp + (size_t)Bb * Tt * NOUT;         // [B][NH]

    unsigned int* gflags = flags + g * 64;
    const int myflag = s * 4 + w;

    for (int t = 0; t < Tt; ++t) {
        // prefetch x fragment (independent of peers -> hides under flag wait)
        const short8 ax = cvt8(x + ((size_t)(r0 + l15) * Tt + t) * NIN + w * 32 + q * 8);

        if (t > 0) {
            // every wave polls all 64 group flags itself: lane l -> flag l
            const unsigned int* fp = gflags + l;
            while (__hip_atomic_load(fp, __ATOMIC_RELAXED,
                                     __HIP_MEMORY_SCOPE_AGENT) < (unsigned)t)
                __builtin_amdgcn_s_sleep(1);
        }
        asm volatile("" ::: "memory");  // keep ah loads below the poll

        // ---- A fragments: A[m][k], m = lane&15 (batch row), k contiguous ----
        short8 ah[4];
        if (t == 0) {
            for (int i = 0; i < 4; ++i)
                ah[i] = cvt8(h0 + (size_t)(r0 + l15) * NH + (4 * w + i) * 32 + q * 8);
        } else {
            const unsigned short* hb = Hx + (size_t)((t - 1) & 1) * Bb * NH
                                          + (size_t)(r0 + l15) * NH;
            for (int i = 0; i < 4; ++i)
                ah[i] = ld_frag_cp(hb + (4 * w + i) * 32 + q * 8);
        }

        // ---- MFMA: each wave covers K quarter (128 of Whh + 32 of Wih) ----
        for (int nt = 0; nt < 2; ++nt) {
            float4v acc = {0.f, 0.f, 0.f, 0.f};
            for (int i = 0; i < 4; ++i)
                acc = __builtin_amdgcn_mfma_f32_16x16x32_bf16(ah[i], fw_hh[nt][i], acc, 0, 0, 0);
            acc = __builtin_amdgcn_mfma_f32_16x16x32_bf16(ax, fw_ih[nt], acc, 0, 0, 0);
            // D layout: m = quad*4 + reg, n = lane&15
            *(float4v*)&Cred[(((w * 2 + nt) * 4 + q) * 16 + l15) * 4] = acc;
        }
        if (do_out) {   // fused out-proj partial: out_{t-1} tile, same ah
            float4v acc2 = {0.f, 0.f, 0.f, 0.f};
            for (int i = 0; i < 4; ++i)
                acc2 = __builtin_amdgcn_mfma_f32_16x16x32_bf16(ah[i], fw_out[i], acc2, 0, 0, 0);
            *(float4v*)&Cred2[((w * 4 + q) * 16 + l15) * 4] = acc2;
        }
        __syncthreads();

        // ---- cross-wave K reduction + fused epilogue ----
        const int nt0 = ucol >> 4,       n0 = ucol & 15;
        const int nt1 = (ucol + 1) >> 4, n1 = (ucol + 1) & 15;
        const int qq = urow >> 2, rr = urow & 3;
        float s0 = 0.f, s1 = 0.f;
        for (int ww = 0; ww < 4; ++ww) {
            s0 += Cred[(((ww * 2 + nt0) * 4 + qq) * 16 + n0) * 4 + rr];
            s1 += Cred[(((ww * 2 + nt1) * 4 + qq) * 16 + n1) * 4 + rr];
        }
        float cand0 = s0 + bias0; cand0 = cand0 > 0.f ? cand0 : 0.f;
        float cand1 = s1 + bias1; cand1 = cand1 > 0.f ? cand1 : 0.f;
        hcur0 = (1.f - al0) * hcur0 + al0 * cand0;
        hcur1 = (1.f - al1) * hcur1 + al1 * cand1;

        // bf16 h to exchange buffer: relaxed agent atomic store (issue early)
        const unsigned int packed = (unsigned)f2b(hcur0) | ((unsigned)f2b(hcur1) << 16);
        __hip_atomic_store(
            (unsigned int*)(Hx + (size_t)(t & 1) * Bb * NH + (size_t)gb * NH + c0 + ucol),
            packed, __ATOMIC_RELAXED, __HIP_MEMORY_SCOPE_AGENT);

        // out-proj reduction overlaps the Hx store drain (LDS reads ~150cy
        // under the ~600-900cy vmcnt(0)); MUST stay before the flag store so
        // per-wave-flag ordering protects Cred2 against next-step writes.
        float oval = 0.f;
        if (do_out) {
            float so = 0.f;
            for (int ww = 0; ww < 4; ++ww)
                so += Cred2[((ww * 4 + qq) * 16 + oc) * 4 + rr];
            oval = so + ob;
        }

        // per-wave release: drain own Hx stores, then publish own wave flag
        asm volatile("s_waitcnt vmcnt(0)" ::: "memory");
        if (l == 0)
            __hip_atomic_store(gflags + myflag, (unsigned)(t + 1),
                               __ATOMIC_RELEASE - __ATOMIC_RELEASE + __ATOMIC_RELAXED,
                               __HIP_MEMORY_SCOPE_AGENT);

        // fp32 outputs AFTER the flag release: off the inter-wg critical path
        const float2v hv = {hcur0, hcur1};
        *(float2v*)(hid_out + ((size_t)gb * Tt + t) * NH + c0 + ucol) = hv;
        if (do_out && t > 0)
            outp[((size_t)gb * Tt + (t - 1)) * NOUT + s * 16 + oc] = oval;
        if (t == Tt - 1)
            *(float2v*)(final_out + (size_t)gb * NH + c0 + ucol) = hv;
    }

    // ---- tail: out_{T-1} from the last exchanged h ----
    if (do_out) {
        const unsigned int* fp = gflags + l;
        while (__hip_atomic_load(fp, __ATOMIC_RELAXED,
                                 __HIP_MEMORY_SCOPE_AGENT) < (unsigned)Tt)
            __builtin_amdgcn_s_sleep(1);
        asm volatile("" ::: "memory");
        const unsigned short* hb = Hx + (size_t)((Tt - 1) & 1) * Bb * NH
                                      + (size_t)(r0 + l15) * NH;
        float4v acc2 = {0.f, 0.f, 0.f, 0.f};
        for (int i = 0; i < 4; ++i)
            acc2 = __builtin_amdgcn_mfma_f32_16x16x32_bf16(
                       ld_frag_cp(hb + (4 * w + i) * 32 + q * 8), fw_out[i], acc2, 0, 0, 0);
        *(float4v*)&Cred2[((w * 4 + q) * 16 + l15) * 4] = acc2;
        __syncthreads();
        const int qq = urow >> 2, rr = urow & 3;
        float so = 0.f;
        for (int ww = 0; ww < 4; ++ww)
            so += Cred2[((ww * 4 + qq) * 16 + oc) * 4 + rr];
        outp[((size_t)gb * Tt + (Tt - 1)) * NOUT + s * 16 + oc] = so + ob;
    }
}

extern "C" void kernel_launch(void* const* d_in, const int* in_sizes, int n_in,
                              void* d_out, int out_size, void* d_ws, size_t ws_size,
                              hipStream_t stream) {
    (void)in_sizes; (void)n_in; (void)out_size; (void)ws_size;
    const float* x     = (const float*)d_in[0];
    const float* h0    = (const float*)d_in[1];
    const float* Wih   = (const float*)d_in[2];
    const float* Whh   = (const float*)d_in[3];
    const float* bih   = (const float*)d_in[4];
    const float* bhh   = (const float*)d_in[5];
    const float* Wout  = (const float*)d_in[6];
    const float* bout  = (const float*)d_in[7];
    const float* alpha = (const float*)d_in[8];
    float* out = (float*)d_out;

    unsigned short* Hx   = (unsigned short*)d_ws;                       // 512 KB
    unsigned int*  flags = (unsigned int*)((char*)d_ws + (size_t)2 * Bb * NH * 2);

    init_flags_kernel<<<4, 256, 0, stream>>>(flags);

    void* args[] = { (void*)&x, (void*)&h0, (void*)&Wih, (void*)&Whh,
                     (void*)&bih, (void*)&bhh, (void*)&alpha,
                     (void*)&Wout, (void*)&bout, (void*)&out,
                     (void*)&Hx, (void*)&flags };
    hipLaunchCooperativeKernel((const void*)rnn_persist, dim3(256), dim3(256),
                               args, 0, stream);
}

// Round 4
// 1936.163 us; speedup vs baseline: 1.7168x; 1.7168x over previous
//
#include <hip/hip_runtime.h>
#include <stdint.h>
#include <stddef.h>

#define Bb   256
#define Tt   500
#define NIN  128
#define NH   512
#define NOUT 64
#define NP   256   // colpairs per row = NH/2

typedef __attribute__((ext_vector_type(8))) short  short8;   // 8 bf16 (4 VGPRs)
typedef __attribute__((ext_vector_type(4))) float  float4v;
typedef __attribute__((ext_vector_type(2))) float  float2v;

__device__ __forceinline__ unsigned short f2b(float f) {
    union { float f; unsigned u; } v; v.f = f;
    unsigned u = v.u;
    unsigned r = (u + 0x7FFFu + ((u >> 16) & 1u)) >> 16;  // RNE
    return (unsigned short)r;
}

// load 8 consecutive fp32 (16B-aligned) and convert to a bf16x8 fragment
__device__ __forceinline__ short8 cvt8(const float* __restrict__ p) {
    const float4v a = *(const float4v*)p;
    const float4v b = *(const float4v*)(p + 4);
    short8 r;
    r[0] = (short)f2b(a[0]); r[1] = (short)f2b(a[1]);
    r[2] = (short)f2b(a[2]); r[3] = (short)f2b(a[3]);
    r[4] = (short)f2b(b[0]); r[5] = (short)f2b(b[1]);
    r[6] = (short)f2b(b[2]); r[7] = (short)f2b(b[3]);
    return r;
}

// clear the tagged exchange buffer: 2*Bb*NP u64 = 131072 entries. <<<512,256>>>
__global__ void init_ws_kernel(unsigned long long* p) {
    p[(size_t)blockIdx.x * 256 + threadIdx.x] = 0ull;
}

// Persistent recurrent kernel with tag-in-data exchange + fused out-proj.
// 256 wgs x 256 thr; wg -> (g = wg&15 batch group, s = wg>>4 hidden slice).
//
// Exchange protocol (flag-free, barrier-free across wgs):
//   Each h entry is one u64 = [hi32: tag = t+1][lo32: 2 packed bf16], stored
//   with a single relaxed agent-scope atomic store into HxT[t&1]. Consumers
//   at step t poll their own 16 u64s until all tags == t (exact match; tags
//   strictly increase, buffer cleared per launch -> no ABA). 8B single-copy
//   atomicity makes tag and data inseparable: no vmcnt drain, no flag store,
//   no acquire/release, ~1 coherence-point RTT per step instead of ~3.
// WAR safety: a thread's tagged store at step t follows its Cred reads
//   (program order); a wg's step-t+1 LDS writes follow its polls of tag t+1,
//   which transitively happen-after every group member's step-t loads and
//   step-t-1 parity readers. LDS Cred/Cred2 are parity double-buffered, so
//   the only intra-wg barrier per step is the Cred join.
__global__ void __launch_bounds__(256) rnn_persist(
    const float* __restrict__ x,      // [B][T][NIN]
    const float* __restrict__ h0,     // [B][NH]
    const float* __restrict__ Wih,    // [NH][NIN]
    const float* __restrict__ Whh,    // [NH][NH]
    const float* __restrict__ bih,    // [NH]
    const float* __restrict__ bhh,    // [NH]
    const float* __restrict__ alpha,  // [NH]
    const float* __restrict__ Wout,   // [NOUT][NH]
    const float* __restrict__ bout,   // [NOUT]
    float* __restrict__ out,          // full output buffer
    unsigned long long* __restrict__ HxT) // ws: [2][B][NP] tagged u64
{
    const int wg  = blockIdx.x;
    const int g   = wg & 15;   // batch group
    const int s   = wg >> 4;   // hidden slice
    const int r0  = g << 4;    // first batch row
    const int c0  = s << 5;    // first hidden col
    const int tid = threadIdx.x;
    const int w   = tid >> 6;  // wave 0..3 (K-split)
    const int l   = tid & 63;
    const int l15 = l & 15;
    const int q   = l >> 4;
    const bool do_out = (s < 4);   // wg-uniform

    // parity-double-buffered partial-C exchange
    __shared__ float Cred [2][4 * 2 * 4 * 16 * 4];
    __shared__ float Cred2[2][4 * 4 * 16 * 4];

    // ---- stationary weight fragments (loaded once, fp32 -> bf16) ----
    // B-frag layout: B[k][n], n = lane&15, k = quad*8 + j (8 contiguous k)
    short8 fw_hh[2][4], fw_ih[2], fw_out[4];
    for (int nt = 0; nt < 2; ++nt) {
        for (int i = 0; i < 4; ++i) {
            const float* p = Whh + (size_t)(c0 + nt * 16 + l15) * NH
                                 + (4 * w + i) * 32 + q * 8;
            fw_hh[nt][i] = cvt8(p);
        }
        fw_ih[nt] = cvt8(Wih + (size_t)(c0 + nt * 16 + l15) * NIN + w * 32 + q * 8);
    }
    if (do_out) {
        for (int i = 0; i < 4; ++i)
            fw_out[i] = cvt8(Wout + (size_t)(s * 16 + l15) * NH + (4 * w + i) * 32 + q * 8);
    }

    // ---- per-thread epilogue state (thread -> (row, 2 cols)) ----
    const int urow = tid >> 4;           // 0..15 batch-local row
    const int ucol = (tid & 15) * 2;     // 0..30 col pair within slice
    const int oc   = tid & 15;           // out col within 16-col tile
    const int gb   = r0 + urow;          // global batch row
    float hcur0 = h0[(size_t)gb * NH + c0 + ucol];
    float hcur1 = h0[(size_t)gb * NH + c0 + ucol + 1];
    const float bias0 = bih[c0 + ucol]     + bhh[c0 + ucol];
    const float bias1 = bih[c0 + ucol + 1] + bhh[c0 + ucol + 1];
    const float al0 = alpha[c0 + ucol], al1 = alpha[c0 + ucol + 1];
    const float ob  = do_out ? bout[s * 16 + oc] : 0.f;

    float* hid_out   = out;                                   // [B][T][NH]
    float* outp      = out + (size_t)Bb * Tt * NH;            // [B][T][NOUT]
    float* final_out = outp + (size_t)Bb * Tt * NOUT;         // [B][NH]

    // producer slot: this thread's (row, colpair)
    const size_t myslot = (size_t)gb * NP + (size_t)(c0 + ucol) / 2;
    // consumer base: rows r0+l15, colpairs w*64 + i*16 + q*4 + jj
    const size_t cbase = (size_t)(r0 + l15) * NP + (size_t)w * 64 + q * 4;
    const int qq = urow >> 2, rr = urow & 3;

    for (int t = 0; t < Tt; ++t) {
        const int par = t & 1;
        // prefetch x fragment (independent of peers -> hides under poll)
        const short8 ax = cvt8(x + ((size_t)(r0 + l15) * Tt + t) * NIN + w * 32 + q * 8);

        // ---- A fragments: poll tagged data (per-wave, no barrier) ----
        short8 ah[4];
        if (t == 0) {
            for (int i = 0; i < 4; ++i)
                ah[i] = cvt8(h0 + (size_t)(r0 + l15) * NH + (4 * w + i) * 32 + q * 8);
        } else {
            const unsigned long long* hb = HxT + (size_t)((t - 1) & 1) * Bb * NP + cbase;
            const unsigned expt = (unsigned)t;
            unsigned long long v[4][4];
            for (;;) {
                bool ok = true;
                #pragma unroll
                for (int i = 0; i < 4; ++i) {
                    #pragma unroll
                    for (int jj = 0; jj < 4; ++jj)
                        v[i][jj] = __hip_atomic_load(hb + i * 16 + jj,
                                                     __ATOMIC_RELAXED,
                                                     __HIP_MEMORY_SCOPE_AGENT);
                }
                #pragma unroll
                for (int i = 0; i < 4; ++i) {
                    #pragma unroll
                    for (int jj = 0; jj < 4; ++jj)
                        ok = ok && ((unsigned)(v[i][jj] >> 32) == expt);
                }
                if (__all((int)ok)) break;
                __builtin_amdgcn_s_sleep(1);
            }
            #pragma unroll
            for (int i = 0; i < 4; ++i) {
                short8 a;
                #pragma unroll
                for (int jj = 0; jj < 4; ++jj) {
                    const unsigned d = (unsigned)v[i][jj];
                    a[2 * jj]     = (short)(unsigned short)(d & 0xffffu);
                    a[2 * jj + 1] = (short)(unsigned short)(d >> 16);
                }
                ah[i] = a;
            }
        }

        // ---- MFMA: each wave covers K quarter (128 of Whh + 32 of Wih) ----
        for (int nt = 0; nt < 2; ++nt) {
            float4v acc = {0.f, 0.f, 0.f, 0.f};
            for (int i = 0; i < 4; ++i)
                acc = __builtin_amdgcn_mfma_f32_16x16x32_bf16(ah[i], fw_hh[nt][i], acc, 0, 0, 0);
            acc = __builtin_amdgcn_mfma_f32_16x16x32_bf16(ax, fw_ih[nt], acc, 0, 0, 0);
            // D layout: m = quad*4 + reg, n = lane&15
            *(float4v*)&Cred[par][(((w * 2 + nt) * 4 + q) * 16 + l15) * 4] = acc;
        }
        if (do_out) {   // fused out-proj partial for out_{t-1} (same ah)
            float4v acc2 = {0.f, 0.f, 0.f, 0.f};
            for (int i = 0; i < 4; ++i)
                acc2 = __builtin_amdgcn_mfma_f32_16x16x32_bf16(ah[i], fw_out[i], acc2, 0, 0, 0);
            *(float4v*)&Cred2[par][((w * 4 + q) * 16 + l15) * 4] = acc2;
        }
        __syncthreads();   // the single per-step barrier

        // ---- cross-wave K reduction + fused epilogue ----
        const int nt0 = ucol >> 4,       n0 = ucol & 15;
        const int nt1 = (ucol + 1) >> 4, n1 = (ucol + 1) & 15;
        float s0 = 0.f, s1 = 0.f;
        for (int ww = 0; ww < 4; ++ww) {
            s0 += Cred[par][(((ww * 2 + nt0) * 4 + qq) * 16 + n0) * 4 + rr];
            s1 += Cred[par][(((ww * 2 + nt1) * 4 + qq) * 16 + n1) * 4 + rr];
        }
        float cand0 = s0 + bias0; cand0 = cand0 > 0.f ? cand0 : 0.f;
        float cand1 = s1 + bias1; cand1 = cand1 > 0.f ? cand1 : 0.f;
        hcur0 = (1.f - al0) * hcur0 + al0 * cand0;
        hcur1 = (1.f - al1) * hcur1 + al1 * cand1;

        // ---- tagged h publish: ONE relaxed agent atomic u64, fire&forget ----
        const unsigned packed = (unsigned)f2b(hcur0) | ((unsigned)f2b(hcur1) << 16);
        const unsigned long long tagged =
            ((unsigned long long)(unsigned)(t + 1) << 32) | (unsigned long long)packed;
        __hip_atomic_store(HxT + (size_t)par * Bb * NP + myslot, tagged,
                           __ATOMIC_RELAXED, __HIP_MEMORY_SCOPE_AGENT);

        // ---- shadow region: overlaps peers' store flight / next poll ----
        const float2v hv = {hcur0, hcur1};
        *(float2v*)(hid_out + ((size_t)gb * Tt + t) * NH + c0 + ucol) = hv;
        if (t == Tt - 1)
            *(float2v*)(final_out + (size_t)gb * NH + c0 + ucol) = hv;
        if (do_out && t > 0) {
            float so = 0.f;
            for (int ww = 0; ww < 4; ++ww)
                so += Cred2[par][((ww * 4 + qq) * 16 + oc) * 4 + rr];
            outp[((size_t)gb * Tt + (t - 1)) * NOUT + s * 16 + oc] = so + ob;
        }
    }

    // ---- tail: out_{T-1} from the last exchanged h (parity (Tt-1)&1, tag Tt) ----
    if (do_out) {
        const unsigned long long* hb = HxT + (size_t)((Tt - 1) & 1) * Bb * NP + cbase;
        const unsigned expt = (unsigned)Tt;
        unsigned long long v[4][4];
        for (;;) {
            bool ok = true;
            #pragma unroll
            for (int i = 0; i < 4; ++i) {
                #pragma unroll
                for (int jj = 0; jj < 4; ++jj)
                    v[i][jj] = __hip_atomic_load(hb + i * 16 + jj,
                                                 __ATOMIC_RELAXED,
                                                 __HIP_MEMORY_SCOPE_AGENT);
            }
            #pragma unroll
            for (int i = 0; i < 4; ++i) {
                #pragma unroll
                for (int jj = 0; jj < 4; ++jj)
                    ok = ok && ((unsigned)(v[i][jj] >> 32) == expt);
            }
            if (__all((int)ok)) break;
            __builtin_amdgcn_s_sleep(1);
        }
        float4v acc2 = {0.f, 0.f, 0.f, 0.f};
        #pragma unroll
        for (int i = 0; i < 4; ++i) {
            short8 a;
            #pragma unroll
            for (int jj = 0; jj < 4; ++jj) {
                const unsigned d = (unsigned)v[i][jj];
                a[2 * jj]     = (short)(unsigned short)(d & 0xffffu);
                a[2 * jj + 1] = (short)(unsigned short)(d >> 16);
            }
            acc2 = __builtin_amdgcn_mfma_f32_16x16x32_bf16(a, fw_out[i], acc2, 0, 0, 0);
        }
        // parity Tt&1 = 0: distinct from loop's last Cred2 reads (par 1)
        *(float4v*)&Cred2[Tt & 1][((w * 4 + q) * 16 + l15) * 4] = acc2;
        __syncthreads();
        float so = 0.f;
        for (int ww = 0; ww < 4; ++ww)
            so += Cred2[Tt & 1][((ww * 4 + qq) * 16 + oc) * 4 + rr];
        outp[((size_t)gb * Tt + (Tt - 1)) * NOUT + s * 16 + oc] = so + ob;
    }
}

extern "C" void kernel_launch(void* const* d_in, const int* in_sizes, int n_in,
                              void* d_out, int out_size, void* d_ws, size_t ws_size,
                              hipStream_t stream) {
    (void)in_sizes; (void)n_in; (void)out_size; (void)ws_size;
    const float* x     = (const float*)d_in[0];
    const float* h0    = (const float*)d_in[1];
    const float* Wih   = (const float*)d_in[2];
    const float* Whh   = (const float*)d_in[3];
    const float* bih   = (const float*)d_in[4];
    const float* bhh   = (const float*)d_in[5];
    const float* Wout  = (const float*)d_in[6];
    const float* bout  = (const float*)d_in[7];
    const float* alpha = (const float*)d_in[8];
    float* out = (float*)d_out;

    unsigned long long* HxT = (unsigned long long*)d_ws;   // 1 MB tagged buffer

    init_ws_kernel<<<512, 256, 0, stream>>>(HxT);

    void* args[] = { (void*)&x, (void*)&h0, (void*)&Wih, (void*)&Whh,
                     (void*)&bih, (void*)&bhh, (void*)&alpha,
                     (void*)&Wout, (void*)&bout, (void*)&out, (void*)&HxT };
    hipLaunchCooperativeKernel((const void*)rnn_persist, dim3(256), dim3(256),
                               args, 0, stream);
}